// Round 2
// baseline (8061.592 us; speedup 1.0000x reference)
//
#include <hip/hip_runtime.h>
#include <hip/hip_bf16.h>
#include <stdint.h>

// Problem constants
#define BB   64
#define TT   512
#define DIN  512
#define HH   1024
#define DOUT 512

// Scan decomposition: 4 independent batch groups x 16 rows; per group 16 WGs
// each owning a 64-col slice of h; 4 waves/WG K-split (256 each).
#define GROUPS        4
#define ROWS          16
#define WGS_PER_GROUP 16
#define NSLICE        64
#define THREADS       256

typedef __attribute__((ext_vector_type(8))) short frag8;   // 8 x bf16 (4 VGPRs)
typedef __attribute__((ext_vector_type(4))) float f32x4;   // MFMA accumulator

__device__ __forceinline__ float bf2f(unsigned short u) {
  union { unsigned int i; float f; } v; v.i = ((unsigned int)u) << 16; return v.f;
}
__device__ __forceinline__ unsigned short f2bf(float f) {
  union { float f; unsigned int i; } v; v.f = f;
  unsigned int x = v.i;
  x += 0x7fffu + ((x >> 16) & 1u);   // round-to-nearest-even
  return (unsigned short)(x >> 16);
}
// load 8 contiguous fp32, convert to bf16 frag (RNE)
__device__ __forceinline__ frag8 ld8f32(const float* __restrict__ p) {
  frag8 r;
#pragma unroll
  for (int j = 0; j < 8; ++j) r[j] = (short)f2bf(p[j]);
  return r;
}

// h_t = tanh(x_t @ Wih^T + h_{t-1} @ Whh^T + bih + bhh), both GEMMs fused into
// one MFMA accumulator. Weights (fp32 in HBM) preloaded once as bf16 VGPR frags.
template<int KIN, bool STORE_SEQ, bool XF32>
__global__ __launch_bounds__(THREADS, 1)
void rnn_scan(const void*  __restrict__ Xv,    // [BB][TT][KIN] fp32 (L0) or bf16 (L1)
              const float* __restrict__ Wih,   // [HH][KIN] fp32
              const float* __restrict__ Whh,   // [HH][HH] fp32
              const float* __restrict__ bih,   // [HH] fp32
              const float* __restrict__ bhh,   // [HH] fp32
              unsigned short* __restrict__ st0, // [BB][HH] ping (bf16)
              unsigned short* __restrict__ st1, // [BB][HH] pong (bf16)
              unsigned short* __restrict__ seq, // [BB][TT][HH] (layer0 out, bf16)
              unsigned int*  __restrict__ flags) // [GROUPS][TT] arrive counters
{
  constexpr int KIT_IN = KIN / 128;   // per-wave k-iters (KIN / (4 waves * 32))
  constexpr int KIT_HH = HH  / 128;   // 8

  const int wg  = blockIdx.x;
  const int g   = wg / WGS_PER_GROUP;       // batch group
  const int s   = wg % WGS_PER_GROUP;       // N-slice index
  const int j0  = s * NSLICE;               // first output col of this WG
  const int r0  = g * ROWS;                 // first batch row of this group
  const int tid = threadIdx.x;
  const int w   = tid >> 6;                 // wave 0..3 (K-split)
  const int l   = tid & 63;
  const int lm  = l & 15;                   // m (A) / n (B) within 16-tile
  const int lq  = l >> 4;                   // k-quad

  // ---- preload weight B-fragments into registers (fp32 -> bf16 once) ----
  // B-frag: lane holds W[n = tile+lm][k = base + lq*8 .. +7]
  frag8 wih_f[KIT_IN][4];
  frag8 whh_f[KIT_HH][4];
#pragma unroll
  for (int kit = 0; kit < KIT_IN; ++kit) {
#pragma unroll
    for (int nt = 0; nt < 4; ++nt) {
      int n = j0 + nt * 16 + lm;
      int k = w * (KIN / 4) + kit * 32 + lq * 8;
      wih_f[kit][nt] = ld8f32(Wih + (size_t)n * KIN + k);
    }
  }
#pragma unroll
  for (int kit = 0; kit < KIT_HH; ++kit) {
#pragma unroll
    for (int nt = 0; nt < 4; ++nt) {
      int n = j0 + nt * 16 + lm;
      int k = w * (HH / 4) + kit * 32 + lq * 8;
      whh_f[kit][nt] = ld8f32(Whh + (size_t)n * HH + k);
    }
  }

  // epilogue: wave w owns quadrant nt==w; lane handles col jb, rows lq*4+r
  const int jb = j0 + w * 16 + lm;
  const float biasv = bih[jb] + bhh[jb];

  // K-split partials: [wave][nt][16 rows][16 cols], row stride 17 (pad)
  __shared__ float parts[4 * 4 * 16 * 17];

  unsigned int* flagp = flags + g * TT;

  for (int t = 0; t < TT; ++t) {
    const unsigned short* stR = (t & 1) ? st1 : st0;
    unsigned short*       stW = (t & 1) ? st0 : st1;

    f32x4 acc[4];
#pragma unroll
    for (int nt = 0; nt < 4; ++nt) acc[nt] = (f32x4){0.f, 0.f, 0.f, 0.f};

    // fused input projection: x_t @ Wih^T (K-split across waves)
#pragma unroll
    for (int kit = 0; kit < KIT_IN; ++kit) {
      int k = w * (KIN / 4) + kit * 32 + lq * 8;
      frag8 a;
      if constexpr (XF32) {
        const float* xrow = (const float*)Xv
            + (size_t)(r0 + lm) * TT * KIN + (size_t)t * KIN + k;
        a = ld8f32(xrow);
      } else {
        const unsigned short* xrow = (const unsigned short*)Xv
            + (size_t)(r0 + lm) * TT * KIN + (size_t)t * KIN + k;
        a = *(const frag8*)xrow;
      }
#pragma unroll
      for (int nt = 0; nt < 4; ++nt)
        acc[nt] = __builtin_amdgcn_mfma_f32_16x16x32_bf16(a, wih_f[kit][nt], acc[nt], 0, 0, 0);
    }

    // recurrence: h_{t-1} @ Whh^T (K-split across waves)
    const unsigned short* hrow = stR + (size_t)(r0 + lm) * HH;
#pragma unroll
    for (int kit = 0; kit < KIT_HH; ++kit) {
      int k = w * (HH / 4) + kit * 32 + lq * 8;
      frag8 a = *(const frag8*)(hrow + k);
#pragma unroll
      for (int nt = 0; nt < 4; ++nt)
        acc[nt] = __builtin_amdgcn_mfma_f32_16x16x32_bf16(a, whh_f[kit][nt], acc[nt], 0, 0, 0);
    }

    // ---- cross-wave K reduction via LDS ----
    // C/D layout: col = lane&15, row = (lane>>4)*4 + reg  [verified m89/m91]
#pragma unroll
    for (int nt = 0; nt < 4; ++nt) {
#pragma unroll
      for (int r = 0; r < 4; ++r)
        parts[((w * 4 + nt) * 16 + lq * 4 + r) * 17 + lm] = acc[nt][r];
    }
    __syncthreads();

#pragma unroll
    for (int r = 0; r < 4; ++r) {
      int row = lq * 4 + r;
      float sm = parts[((0 * 4 + w) * 16 + row) * 17 + lm]
               + parts[((1 * 4 + w) * 16 + row) * 17 + lm]
               + parts[((2 * 4 + w) * 16 + row) * 17 + lm]
               + parts[((3 * 4 + w) * 16 + row) * 17 + lm];
      float u = sm + biasv;
      // tanh(u) = 1 - 2/(e^{2u}+1); __expf handles +-inf limits correctly
      float e = __expf(2.0f * u);
      float hval = 1.0f - 2.0f / (e + 1.0f);
      unsigned short hb = f2bf(hval);
      int m = r0 + row;
      stW[(size_t)m * HH + jb] = hb;
      if constexpr (STORE_SEQ)
        seq[(size_t)m * TT * HH + (size_t)t * HH + jb] = hb;
    }

    // ---- 16-wide group barrier (release -> arrive -> spin -> acquire) ----
    __syncthreads();                 // drains all waves' stores (vmcnt 0)
    if (tid == 0) {
      __threadfence();               // release: wb L2 to LLC
      atomicAdd(flagp + t, 1u);      // device-scope
      while (__hip_atomic_load(flagp + t, __ATOMIC_RELAXED, __HIP_MEMORY_SCOPE_AGENT)
             < (unsigned)WGS_PER_GROUP)
        __builtin_amdgcn_s_sleep(1);
      __threadfence();               // acquire: invalidate before reading peers' h
    }
    __syncthreads();
  }
}

__global__ void zero_kernel(unsigned int* __restrict__ p, int n) {
  int i  = blockIdx.x * blockDim.x + threadIdx.x;
  int st = gridDim.x * blockDim.x;
  for (; i < n; i += st) p[i] = 0u;
}

// out[m][n] = h2_last[m] . Wfc[n] + bfc[n]   (64x512x1024, tiny)
__global__ void fc_kernel(const unsigned short* __restrict__ h2,  // bf16
                          const float* __restrict__ Wfc,          // fp32
                          const float* __restrict__ bfc,          // fp32
                          float* __restrict__ out)                // fp32
{
  int idx = blockIdx.x * blockDim.x + threadIdx.x;  // 32768 = 64*512
  int m = idx >> 9;
  int n = idx & 511;
  const unsigned short* hp = h2  + (size_t)m * HH;
  const float*          wp = Wfc + (size_t)n * HH;
  float acc = 0.f;
#pragma unroll 4
  for (int k = 0; k < HH; k += 4) {
    ushort4 hv = *(const ushort4*)(hp + k);
    float4  wv = *(const float4*)(wp + k);
    acc += bf2f(hv.x) * wv.x + bf2f(hv.y) * wv.y
         + bf2f(hv.z) * wv.z + bf2f(hv.w) * wv.w;
  }
  out[idx] = acc + bfc[n];
}

extern "C" void kernel_launch(void* const* d_in, const int* in_sizes, int n_in,
                              void* d_out, int out_size, void* d_ws, size_t ws_size,
                              hipStream_t stream)
{
  const float* x    = (const float*)d_in[0];
  const float* Wih0 = (const float*)d_in[1];
  const float* Whh0 = (const float*)d_in[2];
  const float* bih0 = (const float*)d_in[3];
  const float* bhh0 = (const float*)d_in[4];
  const float* Wih1 = (const float*)d_in[5];
  const float* Whh1 = (const float*)d_in[6];
  const float* bih1 = (const float*)d_in[7];
  const float* bhh1 = (const float*)d_in[8];
  const float* Wfc  = (const float*)d_in[9];
  const float* bfc  = (const float*)d_in[10];

  // ws layout: h1seq (64MB bf16) | 4 state buffers (512KB) | flags (16KB)
  unsigned char* ws = (unsigned char*)d_ws;
  unsigned short* h1seq  = (unsigned short*)ws;
  unsigned short* states = (unsigned short*)(ws + (size_t)BB * TT * HH * 2);
  unsigned short* st00 = states;
  unsigned short* st01 = states + (size_t)BB * HH;
  unsigned short* st10 = states + 2 * (size_t)BB * HH;
  unsigned short* st11 = states + 3 * (size_t)BB * HH;
  unsigned int* flags  = (unsigned int*)(ws + (size_t)BB * TT * HH * 2
                                            + 4 * (size_t)BB * HH * 2);
  unsigned int* flags0 = flags;
  unsigned int* flags1 = flags + GROUPS * TT;

  // zero states + flags (ws is poisoned 0xAA before every timed launch)
  int zero_dwords = (4 * BB * HH * 2 + 2 * GROUPS * TT * 4) / 4;
  zero_kernel<<<128, 256, 0, stream>>>((unsigned int*)states, zero_dwords);

  // layer 0: input x fp32 (KIN=512), stores full h1 sequence (bf16)
  rnn_scan<DIN, true,  true ><<<GROUPS * WGS_PER_GROUP, THREADS, 0, stream>>>(
      (const void*)x, Wih0, Whh0, bih0, bhh0, st00, st01, h1seq, flags0);

  // layer 1: input h1seq bf16 (KIN=1024), only final state needed
  rnn_scan<HH, false, false><<<GROUPS * WGS_PER_GROUP, THREADS, 0, stream>>>(
      (const void*)h1seq, Wih1, Whh1, bih1, bhh1, st10, st11, nullptr, flags1);

  // t=511 (odd) writes ping buffer -> final h2 is in st10
  fc_kernel<<<(BB * DOUT) / 256, 256, 0, stream>>>(st10, Wfc, bfc,
                                                   (float*)d_out);
}

// Round 3
// 3481.557 us; speedup vs baseline: 2.3155x; 2.3155x over previous
//
#include <hip/hip_runtime.h>
#include <stdint.h>

// Problem constants
#define BB   64
#define TT   512
#define DIN  512
#define HH   1024
#define DOUT 512

// 4 independent batch groups x 16 rows; per group 16 WGs each owning 64 cols;
// 4 waves/WG K-split (256 K each). Layer 1 runs concurrently (WGs 64..127),
// consuming layer 0's h1seq per-step via LLC flags.
#define GROUPS        4
#define ROWS          16
#define WGS_PER_GROUP 16
#define NSLICE        64
#define THREADS       256
#define WAVES_PER_GROUP (WGS_PER_GROUP * 4)   // flag target = 64 arrivals

typedef __attribute__((ext_vector_type(8))) short frag8;   // 8 x bf16 (4 VGPRs)
typedef __attribute__((ext_vector_type(4))) float f32x4;   // MFMA accumulator

union U64F8 { uint64_t q[2]; frag8 f; };

__device__ __forceinline__ float bf2f(unsigned short u) {
  union { unsigned int i; float f; } v; v.i = ((unsigned int)u) << 16; return v.f;
}
__device__ __forceinline__ unsigned short f2bf(float f) {
  union { float f; unsigned int i; } v; v.f = f;
  unsigned int x = v.i;
  x += 0x7fffu + ((x >> 16) & 1u);   // round-to-nearest-even
  return (unsigned short)(x >> 16);
}
__device__ __forceinline__ frag8 ld8f32(const float* p) {
  frag8 r;
#pragma unroll
  for (int j = 0; j < 8; ++j) r[j] = (short)f2bf(p[j]);
  return r;
}

// ---- LLC-coherent (sc1) access: bypasses per-XCD L2 state, no wbl2/inv ----
__device__ __forceinline__ uint64_t ld64_llc(const unsigned short* p) {
  return __hip_atomic_load((const uint64_t*)p, __ATOMIC_RELAXED, __HIP_MEMORY_SCOPE_AGENT);
}
__device__ __forceinline__ void st64_llc(unsigned short* p, uint64_t v) {
  __hip_atomic_store((uint64_t*)p, v, __ATOMIC_RELAXED, __HIP_MEMORY_SCOPE_AGENT);
}
__device__ __forceinline__ frag8 ld_frag_llc(const unsigned short* p) {
  U64F8 u;
  u.q[0] = ld64_llc(p);
  u.q[1] = ld64_llc(p + 4);
  return u.f;
}
__device__ __forceinline__ void spin_ge(const unsigned int* p, unsigned int tgt) {
  while (__hip_atomic_load((unsigned int*)p, __ATOMIC_RELAXED, __HIP_MEMORY_SCOPE_AGENT) < tgt)
    __builtin_amdgcn_s_sleep(1);
}

// One RNN layer scan. L0: X=fp32 x, writes h1seq (state == h1seq rows).
// L1: X=bf16 h1seq (gated by flag_prod), state in st0/st1 ping-pong.
template<int KIN, bool L0>
__device__ void scan_body(const void* Xv,
                          const float* Wih, const float* Whh,
                          const float* bih, const float* bhh,
                          unsigned short* seq,            // h1seq
                          unsigned short* st0, unsigned short* st1,
                          unsigned int* flag_self, const unsigned int* flag_prod,
                          int g, int s, float* parts)
{
  constexpr int KIT_IN = KIN / 128;
  constexpr int KIT_HH = HH  / 128;

  const int j0  = s * NSLICE;
  const int r0  = g * ROWS;
  const int tid = threadIdx.x;
  const int w   = tid >> 6;
  const int l   = tid & 63;
  const int lm  = l & 15;
  const int lq  = l >> 4;

  // ---- preload weights to VGPR frags (fp32 -> bf16 once) ----
  frag8 wih_f[KIT_IN][4];
  frag8 whh_f[KIT_HH][4];
#pragma unroll
  for (int kit = 0; kit < KIT_IN; ++kit)
#pragma unroll
    for (int nt = 0; nt < 4; ++nt) {
      int n = j0 + nt * 16 + lm;
      int k = w * (KIN / 4) + kit * 32 + lq * 8;
      wih_f[kit][nt] = ld8f32(Wih + (size_t)n * KIN + k);
    }
#pragma unroll
  for (int kit = 0; kit < KIT_HH; ++kit)
#pragma unroll
    for (int nt = 0; nt < 4; ++nt) {
      int n = j0 + nt * 16 + lm;
      int k = w * (HH / 4) + kit * 32 + lq * 8;
      whh_f[kit][nt] = ld8f32(Whh + (size_t)n * HH + k);
    }

  // epilogue mapping: thread -> (row = tid&15, 4 contiguous cols at ecg*4)
  const int erow = tid & 15;
  const int ecg  = tid >> 4;
  float bias4[4];
#pragma unroll
  for (int j = 0; j < 4; ++j) {
    int c = j0 + ecg * 4 + j;
    bias4[j] = bih[c] + bhh[c];
  }

  for (int t = 0; t < TT; ++t) {
    f32x4 acc[4];
#pragma unroll
    for (int nt = 0; nt < 4; ++nt) acc[nt] = (f32x4){0.f, 0.f, 0.f, 0.f};

    // producer gate (L1 only): h1seq[t] complete
    if constexpr (!L0) spin_ge(flag_prod + t, WAVES_PER_GROUP);

    // ---- x-projection ----
#pragma unroll
    for (int kit = 0; kit < KIT_IN; ++kit) {
      int k = w * (KIN / 4) + kit * 32 + lq * 8;
      frag8 a;
      if constexpr (L0) {
        a = ld8f32((const float*)Xv + ((size_t)(r0 + lm) * TT + t) * KIN + k);
      } else {
        a = ld_frag_llc((const unsigned short*)Xv + ((size_t)(r0 + lm) * TT + t) * KIN + k);
      }
#pragma unroll
      for (int nt = 0; nt < 4; ++nt)
        acc[nt] = __builtin_amdgcn_mfma_f32_16x16x32_bf16(a, wih_f[kit][nt], acc[nt], 0, 0, 0);
    }

    // ---- recurrence (skip t=0: h0 == 0) ----
    if (t > 0) {
      spin_ge(flag_self + (t - 1), WAVES_PER_GROUP);   // also gates LDS reuse below
      const unsigned short* src;
      if constexpr (L0)
        src = seq + ((size_t)(r0 + lm) * TT + (t - 1)) * HH;
      else
        src = ((t & 1) ? st1 : st0) + (size_t)(r0 + lm) * HH;
#pragma unroll
      for (int kit = 0; kit < KIT_HH; ++kit) {
        int k = w * (HH / 4) + kit * 32 + lq * 8;
        frag8 a = ld_frag_llc(src + k);
#pragma unroll
        for (int nt = 0; nt < 4; ++nt)
          acc[nt] = __builtin_amdgcn_mfma_f32_16x16x32_bf16(a, whh_f[kit][nt], acc[nt], 0, 0, 0);
      }
    }

    // ---- pass1: K-split partials to LDS ----
    // C/D layout: col = lane&15, row = (lane>>4)*4 + reg  [verified m89/m91]
#pragma unroll
    for (int nt = 0; nt < 4; ++nt)
#pragma unroll
      for (int r = 0; r < 4; ++r)
        parts[((w * 4 + nt) * 16 + lq * 4 + r) * 17 + lm] = acc[nt][r];
    __syncthreads();

    // ---- pass2: reduce 4 K-chunks, tanh, pack 4 cols -> one u64 sc1 store ----
    uint64_t hb4 = 0;
#pragma unroll
    for (int j = 0; j < 4; ++j) {
      int c  = ecg * 4 + j;
      int nt = c >> 4;
      int lc = c & 15;
      float sm = parts[((0 * 4 + nt) * 16 + erow) * 17 + lc]
               + parts[((1 * 4 + nt) * 16 + erow) * 17 + lc]
               + parts[((2 * 4 + nt) * 16 + erow) * 17 + lc]
               + parts[((3 * 4 + nt) * 16 + erow) * 17 + lc];
      float u = sm + bias4[j];
      float e = __expf(2.0f * u);                 // tanh via exp, inf-safe
      float hv = 1.0f - 2.0f / (e + 1.0f);
      hb4 |= (uint64_t)f2bf(hv) << (16 * j);
    }
    unsigned short* dst;
    if constexpr (L0)
      dst = seq + ((size_t)(r0 + erow) * TT + t) * HH + j0 + ecg * 4;
    else
      dst = ((t & 1) ? st0 : st1) + (size_t)(r0 + erow) * HH + j0 + ecg * 4;
    st64_llc(dst, hb4);

    // ---- arrive: drain this wave's sc1 stores, then one add per wave ----
    __builtin_amdgcn_s_waitcnt(0);
    if (l == 0)
      __hip_atomic_fetch_add(flag_self + t, 1u, __ATOMIC_RELAXED, __HIP_MEMORY_SCOPE_AGENT);
  }
}

__global__ __launch_bounds__(THREADS, 1)
void rnn_fused(const float* x,
               const float* Wih0, const float* Whh0, const float* bih0, const float* bhh0,
               const float* Wih1, const float* Whh1, const float* bih1, const float* bhh1,
               unsigned short* h1seq, unsigned short* st0, unsigned short* st1,
               unsigned int* flags0, unsigned int* flags1)
{
  __shared__ float parts[4 * 4 * 16 * 17];
  const int wg = blockIdx.x;
  if (wg < GROUPS * WGS_PER_GROUP) {
    const int g = wg / WGS_PER_GROUP, s = wg % WGS_PER_GROUP;
    scan_body<DIN, true>(x, Wih0, Whh0, bih0, bhh0, h1seq, nullptr, nullptr,
                         flags0 + g * TT, nullptr, g, s, parts);
  } else {
    const int wg2 = wg - GROUPS * WGS_PER_GROUP;
    const int g = wg2 / WGS_PER_GROUP, s = wg2 % WGS_PER_GROUP;
    scan_body<HH, false>(h1seq, Wih1, Whh1, bih1, bhh1, h1seq, st0, st1,
                         flags1 + g * TT, flags0 + g * TT, g, s, parts);
  }
}

__global__ void zero_kernel(unsigned int* __restrict__ p, int n) {
  int i  = blockIdx.x * blockDim.x + threadIdx.x;
  int st = gridDim.x * blockDim.x;
  for (; i < n; i += st) p[i] = 0u;
}

// out[m][n] = h2_last[m] . Wfc[n] + bfc[n]
__global__ void fc_kernel(const unsigned short* __restrict__ h2,  // bf16
                          const float* __restrict__ Wfc,          // fp32
                          const float* __restrict__ bfc,          // fp32
                          float* __restrict__ out)                // fp32
{
  int idx = blockIdx.x * blockDim.x + threadIdx.x;  // 32768 = 64*512
  int m = idx >> 9;
  int n = idx & 511;
  const unsigned short* hp = h2  + (size_t)m * HH;
  const float*          wp = Wfc + (size_t)n * HH;
  float acc = 0.f;
#pragma unroll 4
  for (int k = 0; k < HH; k += 4) {
    ushort4 hv = *(const ushort4*)(hp + k);
    float4  wv = *(const float4*)(wp + k);
    acc += bf2f(hv.x) * wv.x + bf2f(hv.y) * wv.y
         + bf2f(hv.z) * wv.z + bf2f(hv.w) * wv.w;
  }
  out[idx] = acc + bfc[n];
}

extern "C" void kernel_launch(void* const* d_in, const int* in_sizes, int n_in,
                              void* d_out, int out_size, void* d_ws, size_t ws_size,
                              hipStream_t stream)
{
  const float* x    = (const float*)d_in[0];
  const float* Wih0 = (const float*)d_in[1];
  const float* Whh0 = (const float*)d_in[2];
  const float* bih0 = (const float*)d_in[3];
  const float* bhh0 = (const float*)d_in[4];
  const float* Wih1 = (const float*)d_in[5];
  const float* Whh1 = (const float*)d_in[6];
  const float* bih1 = (const float*)d_in[7];
  const float* bhh1 = (const float*)d_in[8];
  const float* Wfc  = (const float*)d_in[9];
  const float* bfc  = (const float*)d_in[10];

  // ws layout: h1seq (64MB bf16) | st0,st1 (128KB each) | flags0,flags1 (8KB each)
  unsigned char* ws = (unsigned char*)d_ws;
  unsigned short* h1seq = (unsigned short*)ws;
  unsigned short* st0   = (unsigned short*)(ws + (size_t)BB * TT * HH * 2);
  unsigned short* st1   = st0 + (size_t)BB * HH;
  unsigned int*  flags0 = (unsigned int*)(ws + (size_t)BB * TT * HH * 2
                                             + 2 * (size_t)BB * HH * 2);
  unsigned int*  flags1 = flags0 + GROUPS * TT;

  // zero the flag arrays (ws is poisoned 0xAA before every timed launch)
  zero_kernel<<<8, 256, 0, stream>>>(flags0, 2 * GROUPS * TT);

  // fused 2-layer pipelined scan: WGs 0..63 = layer 0, 64..127 = layer 1
  rnn_fused<<<2 * GROUPS * WGS_PER_GROUP, THREADS, 0, stream>>>(
      x, Wih0, Whh0, bih0, bhh0, Wih1, Whh1, bih1, bhh1,
      h1seq, st0, st1, flags0, flags1);

  // t=511 (odd) writes st0 -> final h2 in st0
  fc_kernel<<<(BB * DOUT) / 256, 256, 0, stream>>>(st0, Wfc, bfc, (float*)d_out);
}

// Round 5
// 2405.477 us; speedup vs baseline: 3.3513x; 1.4473x over previous
//
#include <hip/hip_runtime.h>
#include <stdint.h>

// Problem constants
#define BB   64
#define TT   512
#define DIN  512
#define HH   1024
#define DOUT 512

// 4 independent batch groups x 16 rows; per group 16 WGs each owning 64 cols;
// 8 waves/WG K-split (128 K each; keeps weight frags <= 128 VGPR, no spills).
// Layer 1 runs concurrently (WGs 64..127), consuming h1seq per-step via flags.
#define GROUPS        4
#define ROWS          16
#define WGS_PER_GROUP 16
#define NSLICE        64
#define THREADS       512
#define NW            8

typedef __attribute__((ext_vector_type(8))) short frag8;        // 8 x bf16
typedef __attribute__((ext_vector_type(4))) float f32x4;        // MFMA acc
typedef __attribute__((ext_vector_type(4))) unsigned int u32x4; // asm payload

union U4F8 { u32x4 u; frag8 f; };

__device__ __forceinline__ float bf2f(unsigned short u) {
  union { unsigned int i; float f; } v; v.i = ((unsigned int)u) << 16; return v.f;
}
__device__ __forceinline__ unsigned short f2bf(float f) {
  union { float f; unsigned int i; } v; v.f = f;
  unsigned int x = v.i;
  x += 0x7fffu + ((x >> 16) & 1u);   // RNE
  return (unsigned short)(x >> 16);
}
__device__ __forceinline__ frag8 ld8f32(const float* p) {
  frag8 r;
#pragma unroll
  for (int j = 0; j < 8; ++j) r[j] = (short)f2bf(p[j]);
  return r;
}

// ---- batched device-scope (sc1) loads: issue all, ONE waitcnt ----
// NOTE: "=&v" early-clobber is REQUIRED — outputs are written by the first
// load while the pointer input is still needed by the later ones. Round 4's
// "=v" let LLVM alias an output tuple with the address pair -> wild loads.
__device__ __forceinline__ void ldx4_sc1(frag8 a[4], const unsigned short* p) {
  u32x4 t0, t1, t2, t3;
  asm volatile(
      "global_load_dwordx4 %0, %4, off sc1\n\t"
      "global_load_dwordx4 %1, %4, off offset:64 sc1\n\t"
      "global_load_dwordx4 %2, %4, off offset:128 sc1\n\t"
      "global_load_dwordx4 %3, %4, off offset:192 sc1\n\t"
      "s_waitcnt vmcnt(0)"
      : "=&v"(t0), "=&v"(t1), "=&v"(t2), "=&v"(t3)
      : "v"(p)
      : "memory");
  U4F8 u;
  u.u = t0; a[0] = u.f;  u.u = t1; a[1] = u.f;
  u.u = t2; a[2] = u.f;  u.u = t3; a[3] = u.f;
}
__device__ __forceinline__ void ldx8_sc1(frag8 a[4], frag8 b[4],
                                         const unsigned short* pa,
                                         const unsigned short* pb) {
  u32x4 t0, t1, t2, t3, s0, s1, s2, s3;
  asm volatile(
      "global_load_dwordx4 %0, %8, off sc1\n\t"
      "global_load_dwordx4 %1, %8, off offset:64 sc1\n\t"
      "global_load_dwordx4 %2, %8, off offset:128 sc1\n\t"
      "global_load_dwordx4 %3, %8, off offset:192 sc1\n\t"
      "global_load_dwordx4 %4, %9, off sc1\n\t"
      "global_load_dwordx4 %5, %9, off offset:64 sc1\n\t"
      "global_load_dwordx4 %6, %9, off offset:128 sc1\n\t"
      "global_load_dwordx4 %7, %9, off offset:192 sc1\n\t"
      "s_waitcnt vmcnt(0)"
      : "=&v"(t0), "=&v"(t1), "=&v"(t2), "=&v"(t3),
        "=&v"(s0), "=&v"(s1), "=&v"(s2), "=&v"(s3)
      : "v"(pa), "v"(pb)
      : "memory");
  U4F8 u;
  u.u = t0; a[0] = u.f;  u.u = t1; a[1] = u.f;
  u.u = t2; a[2] = u.f;  u.u = t3; a[3] = u.f;
  u.u = s0; b[0] = u.f;  u.u = s1; b[1] = u.f;
  u.u = s2; b[2] = u.f;  u.u = s3; b[3] = u.f;
}
__device__ __forceinline__ void st32_sc1(unsigned int* p, unsigned int v) {
  asm volatile("global_store_dword %0, %1, off sc1" :: "v"(p), "v"(v) : "memory");
}
__device__ __forceinline__ void drain_vm() {
  asm volatile("s_waitcnt vmcnt(0)" ::: "memory");
}
// poll 16 per-WG flags (one 64B line): lane loads flags[lane&15], ballot all-set
__device__ __forceinline__ void wait_flags16(const unsigned int* fl16) {
  const unsigned int* p = fl16 + (threadIdx.x & 15);
  for (;;) {
    unsigned int v;
    asm volatile("global_load_dword %0, %1, off sc1\n\ts_waitcnt vmcnt(0)"
                 : "=&v"(v) : "v"(p) : "memory");
    if (__ballot(v != 0u) == ~0ull) break;
  }
}

// One RNN layer scan step-loop. L0: X = fp32 x, state lives in h1seq rows.
// L1: X = bf16 h1seq (gated by flag_prod), state in st0/st1 ping-pong.
template<int KIN, bool L0>
__device__ void scan_body(const void* Xv,
                          const float* Wih, const float* Whh,
                          const float* bih, const float* bhh,
                          unsigned short* seq,
                          unsigned short* st0, unsigned short* st1,
                          unsigned int* flag_self, const unsigned int* flag_prod,
                          int g, int s, float* parts)
{
  constexpr int KIT_IN = KIN / (NW * 32);   // L0: 2, L1: 4
  constexpr int KIT_HH = HH  / (NW * 32);   // 4

  const int j0  = s * NSLICE;
  const int r0  = g * ROWS;
  const int tid = threadIdx.x;
  const int w   = tid >> 6;                 // wave 0..7 (K-split)
  const int l   = tid & 63;
  const int lm  = l & 15;
  const int lq  = l >> 4;

  // ---- preload weights to VGPR frags (fp32 -> bf16 once) ----
  // B-frag: lane holds W[n = j0+nt*16+lm][k = w*(K/8) + kit*32 + lq*8 .. +7]
  frag8 wih_f[KIT_IN][4];
  frag8 whh_f[KIT_HH][4];
#pragma unroll
  for (int kit = 0; kit < KIT_IN; ++kit)
#pragma unroll
    for (int nt = 0; nt < 4; ++nt) {
      int n = j0 + nt * 16 + lm;
      int k = w * (KIN / NW) + kit * 32 + lq * 8;
      wih_f[kit][nt] = ld8f32(Wih + (size_t)n * KIN + k);
    }
#pragma unroll
  for (int kit = 0; kit < KIT_HH; ++kit)
#pragma unroll
    for (int nt = 0; nt < 4; ++nt) {
      int n = j0 + nt * 16 + lm;
      int k = w * (HH / NW) + kit * 32 + lq * 8;
      whh_f[kit][nt] = ld8f32(Whh + (size_t)n * HH + k);
    }

  // epilogue: thread -> (row = tid&15, 2 contiguous cols at (tid>>4)*2)
  const int erow = tid & 15;
  const int ecg  = tid >> 4;               // 0..31
  float bias2[2];
#pragma unroll
  for (int j = 0; j < 2; ++j) {
    int c = j0 + ecg * 2 + j;
    bias2[j] = bih[c] + bhh[c];
  }

  for (int t = 0; t < TT; ++t) {
    // L0: issue cached x loads BEFORE the spin (latency hides under the wait)
    float4 xa[KIT_IN * 2];
    if constexpr (L0) {
      const float* xr = (const float*)Xv
          + ((size_t)(r0 + lm) * TT + t) * KIN + w * (KIN / NW) + lq * 8;
#pragma unroll
      for (int kit = 0; kit < KIT_IN; ++kit) {
        xa[2 * kit]     = *(const float4*)(xr + kit * 32);
        xa[2 * kit + 1] = *(const float4*)(xr + kit * 32 + 4);
      }
    }

    // gates
    if constexpr (!L0) wait_flags16(flag_prod + t * 16);
    if (t > 0)         wait_flags16(flag_self + (t - 1) * 16);

    f32x4 acc[4];
#pragma unroll
    for (int nt = 0; nt < 4; ++nt) acc[nt] = (f32x4){0.f, 0.f, 0.f, 0.f};

    if constexpr (L0) {
      // x-projection from registers (already loaded)
#pragma unroll
      for (int kit = 0; kit < KIT_IN; ++kit) {
        frag8 a;
#pragma unroll
        for (int j = 0; j < 4; ++j) {
          a[j]     = (short)f2bf(((const float*)&xa[2 * kit])[j]);
          a[4 + j] = (short)f2bf(((const float*)&xa[2 * kit + 1])[j]);
        }
#pragma unroll
        for (int nt = 0; nt < 4; ++nt)
          acc[nt] = __builtin_amdgcn_mfma_f32_16x16x32_bf16(a, wih_f[kit][nt], acc[nt], 0, 0, 0);
      }
      if (t > 0) {   // recurrence from h1seq[t-1] (one batched LLC round trip)
        frag8 hf[KIT_HH];
        ldx4_sc1(hf, seq + ((size_t)(r0 + lm) * TT + (t - 1)) * HH
                         + w * (HH / NW) + lq * 8);
#pragma unroll
        for (int kit = 0; kit < KIT_HH; ++kit)
#pragma unroll
          for (int nt = 0; nt < 4; ++nt)
            acc[nt] = __builtin_amdgcn_mfma_f32_16x16x32_bf16(hf[kit], whh_f[kit][nt], acc[nt], 0, 0, 0);
      }
    } else {
      const unsigned short* px = (const unsigned short*)Xv
          + ((size_t)(r0 + lm) * TT + t) * KIN + w * (KIN / NW) + lq * 8;
      if (t > 0) {
        const unsigned short* ph = ((t & 1) ? st1 : st0)
            + (size_t)(r0 + lm) * HH + w * (HH / NW) + lq * 8;
        frag8 xf[KIT_IN], hf[KIT_HH];
        ldx8_sc1(xf, hf, px, ph);           // both batches, ONE round trip
#pragma unroll
        for (int kit = 0; kit < KIT_IN; ++kit)
#pragma unroll
          for (int nt = 0; nt < 4; ++nt)
            acc[nt] = __builtin_amdgcn_mfma_f32_16x16x32_bf16(xf[kit], wih_f[kit][nt], acc[nt], 0, 0, 0);
#pragma unroll
        for (int kit = 0; kit < KIT_HH; ++kit)
#pragma unroll
          for (int nt = 0; nt < 4; ++nt)
            acc[nt] = __builtin_amdgcn_mfma_f32_16x16x32_bf16(hf[kit], whh_f[kit][nt], acc[nt], 0, 0, 0);
      } else {
        frag8 xf[KIT_IN];
        ldx4_sc1(xf, px);
#pragma unroll
        for (int kit = 0; kit < KIT_IN; ++kit)
#pragma unroll
          for (int nt = 0; nt < 4; ++nt)
            acc[nt] = __builtin_amdgcn_mfma_f32_16x16x32_bf16(xf[kit], wih_f[kit][nt], acc[nt], 0, 0, 0);
      }
    }

    // ---- pass1: K-split partials to LDS ----
    // C/D layout: col = lane&15, row = (lane>>4)*4 + reg  [verified m89/m91]
#pragma unroll
    for (int nt = 0; nt < 4; ++nt)
#pragma unroll
      for (int r = 0; r < 4; ++r)
        parts[((w * 4 + nt) * 16 + lq * 4 + r) * 17 + lm] = acc[nt][r];
    __syncthreads();

    // ---- pass2: reduce 8 K-chunks, tanh, pack 2 cols -> one dword sc1 store
    unsigned int hb2 = 0;
#pragma unroll
    for (int j = 0; j < 2; ++j) {
      int c  = ecg * 2 + j;
      int nt = c >> 4;
      int lc = c & 15;
      float sm = 0.f;
#pragma unroll
      for (int w8 = 0; w8 < NW; ++w8)
        sm += parts[((w8 * 4 + nt) * 16 + erow) * 17 + lc];
      float u = sm + bias2[j];
      float e = __expf(2.0f * u);               // tanh via exp, inf-safe
      float hv = 1.0f - 2.0f / (e + 1.0f);
      hb2 |= (unsigned int)f2bf(hv) << (16 * j);
    }
    unsigned short* dst;
    if constexpr (L0)
      dst = seq + ((size_t)(r0 + erow) * TT + t) * HH + j0 + ecg * 2;
    else
      dst = ((t & 1) ? st0 : st1) + (size_t)(r0 + erow) * HH + j0 + ecg * 2;
    st32_sc1((unsigned int*)dst, hb2);

    // ---- publish: drain asm stores, barrier, one flag store per WG ----
    drain_vm();            // compiler can't see asm stores; explicit vmcnt(0)
    __syncthreads();       // end barrier also guards LDS `parts` reuse
    if (tid == 0)
      st32_sc1((unsigned int*)(flag_self + t * 16 + s), 1u);
  }
}

__global__ __launch_bounds__(THREADS, 1)
void rnn_fused(const float* x,
               const float* Wih0, const float* Whh0, const float* bih0, const float* bhh0,
               const float* Wih1, const float* Whh1, const float* bih1, const float* bhh1,
               unsigned short* h1seq, unsigned short* st0, unsigned short* st1,
               unsigned int* flags0, unsigned int* flags1)
{
  __shared__ float parts[NW * 4 * 16 * 17];
  const int wg = blockIdx.x;
  if (wg < GROUPS * WGS_PER_GROUP) {
    const int g = wg / WGS_PER_GROUP, s = wg % WGS_PER_GROUP;
    scan_body<DIN, true>(x, Wih0, Whh0, bih0, bhh0, h1seq, nullptr, nullptr,
                         flags0 + (size_t)g * TT * 16, nullptr, g, s, parts);
  } else {
    const int wg2 = wg - GROUPS * WGS_PER_GROUP;
    const int g = wg2 / WGS_PER_GROUP, s = wg2 % WGS_PER_GROUP;
    scan_body<HH, false>(h1seq, Wih1, Whh1, bih1, bhh1, h1seq, st0, st1,
                         flags1 + (size_t)g * TT * 16,
                         flags0 + (size_t)g * TT * 16, g, s, parts);
  }
}

__global__ void zero_kernel(unsigned int* __restrict__ p, int n) {
  int i  = blockIdx.x * blockDim.x + threadIdx.x;
  int st = gridDim.x * blockDim.x;
  for (; i < n; i += st) p[i] = 0u;
}

// out[m][n] = h2_last[m] . Wfc[n] + bfc[n]
__global__ void fc_kernel(const unsigned short* __restrict__ h2,  // bf16
                          const float* __restrict__ Wfc,          // fp32
                          const float* __restrict__ bfc,          // fp32
                          float* __restrict__ out)                // fp32
{
  int idx = blockIdx.x * blockDim.x + threadIdx.x;  // 32768 = 64*512
  int m = idx >> 9;
  int n = idx & 511;
  const unsigned short* hp = h2  + (size_t)m * HH;
  const float*          wp = Wfc + (size_t)n * HH;
  float acc = 0.f;
#pragma unroll 4
  for (int k = 0; k < HH; k += 4) {
    ushort4 hv = *(const ushort4*)(hp + k);
    float4  wv = *(const float4*)(wp + k);
    acc += bf2f(hv.x) * wv.x + bf2f(hv.y) * wv.y
         + bf2f(hv.z) * wv.z + bf2f(hv.w) * wv.w;
  }
  out[idx] = acc + bfc[n];
}

extern "C" void kernel_launch(void* const* d_in, const int* in_sizes, int n_in,
                              void* d_out, int out_size, void* d_ws, size_t ws_size,
                              hipStream_t stream)
{
  const float* x    = (const float*)d_in[0];
  const float* Wih0 = (const float*)d_in[1];
  const float* Whh0 = (const float*)d_in[2];
  const float* bih0 = (const float*)d_in[3];
  const float* bhh0 = (const float*)d_in[4];
  const float* Wih1 = (const float*)d_in[5];
  const float* Whh1 = (const float*)d_in[6];
  const float* bih1 = (const float*)d_in[7];
  const float* bhh1 = (const float*)d_in[8];
  const float* Wfc  = (const float*)d_in[9];
  const float* bfc  = (const float*)d_in[10];

  // ws: h1seq (64MB) | st0,st1 (128KB each) | flags0,flags1 (128KB each)
  unsigned char* ws = (unsigned char*)d_ws;
  unsigned short* h1seq = (unsigned short*)ws;
  unsigned short* st0   = (unsigned short*)(ws + (size_t)BB * TT * HH * 2);
  unsigned short* st1   = st0 + (size_t)BB * HH;
  unsigned int*  flags0 = (unsigned int*)(ws + (size_t)BB * TT * HH * 2
                                             + 2 * (size_t)BB * HH * 2);
  unsigned int*  flags1 = flags0 + (size_t)GROUPS * TT * 16;

  // zero both flag arrays (ws is re-poisoned 0xAA before every timed launch)
  zero_kernel<<<64, 256, 0, stream>>>(flags0, 2 * GROUPS * TT * 16);

  // fused 2-layer pipelined scan: WGs 0..63 = layer 0, 64..127 = layer 1
  rnn_fused<<<2 * GROUPS * WGS_PER_GROUP, THREADS, 0, stream>>>(
      x, Wih0, Whh0, bih0, bhh0, Wih1, Whh1, bih1, bhh1,
      h1seq, st0, st1, flags0, flags1);

  // t=511 (odd) writes st0 -> final h2 in st0
  fc_kernel<<<(BB * DOUT) / 256, 256, 0, stream>>>(st0, Wfc, bfc, (float*)d_out);
}